// Round 12
// baseline (51.401 us; speedup 1.0000x reference)
//
#include <hip/hip_runtime.h>
#include <hip/hip_bf16.h>
#include <math.h>

#define BB 4
#define TT 4096
#define CC 1024
#define HS 64
#define WIN 512
#define NROW (BB*TT)

typedef float f32x4 __attribute__((ext_vector_type(4)));
typedef short bf16x8 __attribute__((ext_vector_type(8)));

#define MFMA16(a, b, c) __builtin_amdgcn_mfma_f32_16x16x32_bf16((a), (b), (c), 0, 0, 0)

#define GLOAD_LDS(gp, lp) __builtin_amdgcn_global_load_lds( \
    (const __attribute__((address_space(1))) void*)(gp), \
    (__attribute__((address_space(3))) void*)(lp), 16, 0, 0)

__device__ inline unsigned short f2b(float f) {
  union { __hip_bfloat16 h; unsigned short u; } v;
  v.h = __float2bfloat16(f);   // HW RNE convert
  return v.u;
}

// ---------------- prep: x f32 -> bf16 stream-convert + pack W ----------------
// grid 2048 x 256 (8 waves/CU-class TLP, copy-benchmark-shaped access).
// xb[row][k] bf16 (33.5 MB). Blocks 0..191 also pack W into MFMA B-fragment
// order: wp[((kt*12+nb)*64+lane)*8+j] = W[kt*32+(lane>>4)*8+j][nb*16+(lane&15)],
// n: 0..63 = w_query, 64..127 = w_key, 128..191 = w_value.
__global__ __launch_bounds__(256) void prep_kernel(
    const float* __restrict__ x,
    const float* __restrict__ wq, const float* __restrict__ wk,
    const float* __restrict__ wv,
    unsigned short* __restrict__ xb, unsigned short* __restrict__ wp)
{
  int t = blockIdx.x * 256 + threadIdx.x;

  // ---- W pack (first 49152 threads) ----
  if (t < 49152) {
    int kg = t / 48;
    int nq = t % 48;
    int n0 = nq * 4;
    int m  = n0 >> 6;
    int c  = n0 & 63;
    const float* w = (m == 0) ? wq : (m == 1) ? wk : wv;
    float4 v = *(const float4*)&w[(size_t)kg * HS + c];
    int kt = kg >> 5;
    int hi = (kg >> 3) & 3;
    int j  = kg & 7;
    float vals[4] = {v.x, v.y, v.z, v.w};
    #pragma unroll
    for (int i = 0; i < 4; ++i) {
      int n  = n0 + i;
      int nb = n >> 4;
      int rl = n & 15;
      int lane = hi * 16 + rl;
      wp[((size_t)(kt * 12 + nb) * 64 + lane) * 8 + j] = f2b(vals[i]);
    }
  }

  // ---- x convert: dense grid-stride, 8 floats (32B read, 16B write) per iter
  const int total = NROW * CC / 8;     // 2097152
  const int stride = 2048 * 256;
  #pragma unroll 1
  for (int i = t; i < total; i += stride) {
    const float* gp = x + (size_t)i * 8;
    f32x4 a0 = *(const f32x4*)gp;
    f32x4 a1 = *(const f32x4*)(gp + 4);
    uint4 pk;
    pk.x = (unsigned)f2b(a0[0]) | ((unsigned)f2b(a0[1]) << 16);
    pk.y = (unsigned)f2b(a0[2]) | ((unsigned)f2b(a0[3]) << 16);
    pk.z = (unsigned)f2b(a1[0]) | ((unsigned)f2b(a1[1]) << 16);
    pk.w = (unsigned)f2b(a1[2]) | ((unsigned)f2b(a1[3]) << 16);
    *(uint4*)(xb + (size_t)i * 8) = pk;
  }
}

// ---------------- Projection via MFMA: [q|k|v] = xb @ W ----------------
// R11 fat-step structure, x now pre-converted bf16 (half the LLC stream).
// BM=64, BK=128 -> 256 blocks (1/CU) x 512 threads (8 waves = 2 rowhalves x
// 4 colquarters), 8 barrier-steps.
// x: global bf16 -> reg (16B) -> XOR-swizzled ds_write_b128 (T14 split).
// W: global_load_lds, fragment-packed linear (48 KB/buf). Double-buffered.
__global__ __launch_bounds__(512) void proj_mfma_kernel(
    const unsigned short* __restrict__ xb, const unsigned short* __restrict__ wp,
    unsigned short* __restrict__ q_ws, unsigned short* __restrict__ k_ws,
    unsigned short* __restrict__ vt_ws)
{
  __shared__ unsigned char lds[131072];  // xb0 16K | xb1 16K | wb0 48K | wb1 48K
  unsigned char* const xb0 = lds;
  unsigned char* const xb1 = lds + 16384;
  unsigned char* const wb0 = lds + 32768;
  unsigned char* const wb1 = lds + 81920;

  const int tid = threadIdx.x;
  const int l   = tid & 63;
  const int wid = tid >> 6;     // 0..7
  const int cq  = wid & 3;      // col quarter (3 nb)
  const int rh  = wid >> 2;     // row half (32 rows)
  const int rl  = l & 15;
  const int hi  = l >> 4;
  const int r0  = blockIdx.x * 64;

  f32x4 acc[2][3];
  #pragma unroll
  for (int g = 0; g < 2; ++g)
    #pragma unroll
    for (int j = 0; j < 3; ++j) acc[g][j] = (f32x4){0.f, 0.f, 0.f, 0.f};

  // x stage: u = it*512+tid; row = u>>4 (0..63); seg = u&15 (16B chunks);
  // 16 lanes = 256B contiguous global per row.
  bf16x8 xr[2];

#define SXL(KS) { \
    _Pragma("unroll") \
    for (int it = 0; it < 2; ++it) { \
      int u = it * 512 + tid; \
      xr[it] = *(const bf16x8*)(xb + (size_t)(r0 + (u >> 4)) * CC + (KS) * 128 + (u & 15) * 8); \
    } }

  // swizzled reg->LDS: byte = row*256 + ((seg^(row&7))<<4)
#define XPACK(XB) { \
    _Pragma("unroll") \
    for (int it = 0; it < 2; ++it) { \
      int u = it * 512 + tid; \
      int row = u >> 4, seg = u & 15; \
      *(bf16x8*)((XB) + row * 256 + (((seg ^ (row & 7))) << 4)) = xr[it]; \
    } }

  // W: 48 KB/step via global_load_lds, linear fragment stream
#define SW(KS, WB) { \
    const unsigned short* wsrc = wp + (size_t)(KS) * 24576; \
    _Pragma("unroll") \
    for (int i = 0; i < 6; ++i) { \
      int s = i * 512 + tid; \
      GLOAD_LDS(wsrc + s * 8, (WB) + s * 16); \
    } }

  // one BK=128 step: 4 kt x (2 A-frags + 3 W-frags -> 6 MFMA)
#define COMP(XB, WB) { \
    _Pragma("unroll") \
    for (int kt = 0; kt < 4; ++kt) { \
      bf16x8 afr[2]; \
      _Pragma("unroll") \
      for (int g = 0; g < 2; ++g) { \
        int row = rh * 32 + g * 16 + rl; \
        int seg = kt * 4 + hi; \
        afr[g] = *(const bf16x8*)((XB) + row * 256 + ((seg ^ (row & 7)) << 4)); \
      } \
      _Pragma("unroll") \
      for (int j = 0; j < 3; ++j) { \
        bf16x8 wf = *(const bf16x8*)((WB) + ((kt * 12 + cq * 3 + j) * 64 + l) * 16); \
        acc[0][j] = MFMA16(afr[0], wf, acc[0][j]); \
        acc[1][j] = MFMA16(afr[1], wf, acc[1][j]); \
      } \
    } }

  // prologue: stage step 0
  SXL(0)
  SW(0, wb0)
  XPACK(xb0)
  __syncthreads();

  #pragma unroll
  for (int ks = 0; ks < 8; ++ks) {
    unsigned char* const xc = (ks & 1) ? xb1 : xb0;
    unsigned char* const wc = (ks & 1) ? wb1 : wb0;
    unsigned char* const xn = (ks & 1) ? xb0 : xb1;
    unsigned char* const wn = (ks & 1) ? wb0 : wb1;
    if (ks < 7) { SXL(ks + 1) SW(ks + 1, wn) }
    COMP(xc, wc)
    if (ks < 7) { XPACK(xn) }
    __syncthreads();
  }
#undef SXL
#undef XPACK
#undef SW
#undef COMP

  // ---- store: nb 0..3 -> q, 4..7 -> k, 8..11 -> v (transposed per 64-chunk)
  #pragma unroll
  for (int g = 0; g < 2; ++g) {
    int rb = r0 + rh * 32 + g * 16;
    #pragma unroll
    for (int j = 0; j < 3; ++j) {
      int nb = cq * 3 + j;
      if (nb < 8) {
        unsigned short* dst = (nb < 4) ? q_ws : k_ws;
        int c = (nb & 3) * 16 + rl;
        #pragma unroll
        for (int r = 0; r < 4; ++r) {
          int row = rb + hi * 4 + r;
          dst[(size_t)row * HS + c] = f2b(acc[g][j][r]);
        }
      } else {
        int ch   = rb >> 6;
        int key0 = (rb & 63) + hi * 4;
        int d = (nb - 8) * 16 + rl;
        unsigned u0 = (unsigned)f2b(acc[g][j][0]) | ((unsigned)f2b(acc[g][j][1]) << 16);
        unsigned u1 = (unsigned)f2b(acc[g][j][2]) | ((unsigned)f2b(acc[g][j][3]) << 16);
        uint2 uu; uu.x = u0; uu.y = u1;
        *(uint2*)(vt_ws + (size_t)ch * 4096 + d * 64 + key0) = uu;
      }
    }
  }
}

// ---------------- Sliding-window flash attention via MFMA ----------------
// grid 256 blocks (b, 64-q tile) x 256 threads (4 waves, 16 q-rows each).
// Swapped QK^T (S^T = K @ Q^T) -> softmax lane-local; P via wave-private LDS;
// PV with V^T staged swizzled.
__global__ __launch_bounds__(256) void attn_mfma_kernel(
    const unsigned short* __restrict__ q_ws, const unsigned short* __restrict__ k_ws,
    const unsigned short* __restrict__ vt_ws, float* __restrict__ out)
{
  __shared__ uint4 smem4[1600];                 // 25600 B
  unsigned char* smem = (unsigned char*)smem4;  // K:[0,8K) Vt:[8K,16K) P:16K+

  const int tid = threadIdx.x;
  const int l   = tid & 63;
  const int wid = tid >> 6;
  const int rl  = l & 15;
  const int hi  = l >> 4;
  const int b   = blockIdx.x >> 6;
  const int qt  = blockIdx.x & 63;
  const int t0  = qt * 64;
  const int t0w = t0 + wid * 16;

  // Q B-fragments (held in registers): lane = q row t0w+rl, d = hi*8+j (+32)
  const unsigned short* qrow = q_ws + (size_t)(b * TT + t0w + rl) * HS;
  bf16x8 qb0 = *(const bf16x8*)(qrow + hi * 8);
  bf16x8 qb1 = *(const bf16x8*)(qrow + 32 + hi * 8);

  f32x4 oacc[4];
  #pragma unroll
  for (int i = 0; i < 4; ++i) oacc[i] = (f32x4){0.f, 0.f, 0.f, 0.f};
  float m_run = -INFINITY, l_run = 0.f;

  int s_lo = t0 - WIN; if (s_lo < 0) s_lo = 0;
  unsigned char* pbase = smem + 16384 + wid * 2304 + rl * 144;

  for (int sc = s_lo; sc < t0 + 64; sc += 64) {
    __syncthreads();
    // ---- stage K and Vt chunk (64x64 bf16 each), XOR-swizzled rows ----
    {
      const unsigned short* kg = k_ws + (size_t)(b * TT + sc) * HS;
      const unsigned short* vg = vt_ws + (size_t)((b * TT + sc) >> 6) * 4096;
      #pragma unroll
      for (int i = 0; i < 2; ++i) {
        int idx = tid + i * 256;
        int row = idx >> 3;
        int c16 = idx & 7;
        uint4 kv = *(const uint4*)(kg + row * 64 + c16 * 8);
        uint4 vv = *(const uint4*)(vg + row * 64 + c16 * 8);
        *(uint4*)(smem + row * 128 + ((c16 ^ (row & 7)) * 16)) = kv;
        *(uint4*)(smem + 8192 + row * 128 + ((c16 ^ (row & 7)) * 16)) = vv;
      }
    }
    __syncthreads();

    // ---- S^T = K @ Q^T : 4 key-block fragments ----
    f32x4 sacc[4];
    #pragma unroll
    for (int i = 0; i < 4; ++i) sacc[i] = (f32x4){0.f, 0.f, 0.f, 0.f};
    #pragma unroll
    for (int kb = 0; kb < 4; ++kb) {
      int row = kb * 16 + rl;
      unsigned char* kr = smem + row * 128;
      bf16x8 k0 = *(const bf16x8*)(kr + (((hi) ^ (row & 7)) * 16));
      bf16x8 k1 = *(const bf16x8*)(kr + (((4 + hi) ^ (row & 7)) * 16));
      sacc[kb] = MFMA16(k0, qb0, sacc[kb]);
      sacc[kb] = MFMA16(k1, qb1, sacc[kb]);
    }

    // ---- mask + scale + online softmax (lane owns one q = t0w+rl) ----
    const int tg = t0w + rl;
    float p[16];
    float tm = -INFINITY;
    bool full = (sc + 63 <= t0w) && (sc >= t0w - 496);
    #pragma unroll
    for (int kb = 0; kb < 4; ++kb)
      #pragma unroll
      for (int r = 0; r < 4; ++r) {
        float v = sacc[kb][r] * 0.125f;
        if (!full) {
          int key = sc + kb * 16 + hi * 4 + r;
          int diff = tg - key;
          v = (diff >= 0 && diff < WIN) ? v : -INFINITY;
        }
        p[kb * 4 + r] = v;
        tm = fmaxf(tm, v);
      }
    tm = fmaxf(tm, __shfl_xor(tm, 16));
    tm = fmaxf(tm, __shfl_xor(tm, 32));
    float m_new = fmaxf(m_run, tm);
    float fac  = (m_new == -INFINITY) ? 1.f : __expf(m_run - m_new);
    float msub = (m_new == -INFINITY) ? 0.f : m_new;
    float lsum = 0.f;
    #pragma unroll
    for (int i = 0; i < 16; ++i) { p[i] = __expf(p[i] - msub); lsum += p[i]; }
    lsum += __shfl_xor(lsum, 16);
    lsum += __shfl_xor(lsum, 32);
    l_run = l_run * fac + lsum;
    m_run = m_new;

    // ---- P -> wave-private LDS (row q=rl, stride 144 B) ----
    #pragma unroll
    for (int kb = 0; kb < 4; ++kb) {
      unsigned u0 = (unsigned)f2b(p[kb * 4 + 0]) | ((unsigned)f2b(p[kb * 4 + 1]) << 16);
      unsigned u1 = (unsigned)f2b(p[kb * 4 + 2]) | ((unsigned)f2b(p[kb * 4 + 3]) << 16);
      uint2 uu; uu.x = u0; uu.y = u1;
      *(uint2*)(pbase + kb * 32 + hi * 8) = uu;
    }

    // ---- rescale O by fac (redistribute to PV C-layout q = hi*4+r) ----
    #pragma unroll
    for (int r = 0; r < 4; ++r) {
      float fr = __shfl(fac, (l & 48) | (hi * 4 + r));
      oacc[0][r] *= fr; oacc[1][r] *= fr; oacc[2][r] *= fr; oacc[3][r] *= fr;
    }

    // ---- PV: O[q][d] += P @ V ----
    bf16x8 pa0 = *(const bf16x8*)(pbase + hi * 16);
    bf16x8 pa1 = *(const bf16x8*)(pbase + 64 + hi * 16);
    #pragma unroll
    for (int f = 0; f < 4; ++f) {
      int d = f * 16 + rl;
      unsigned char* vr = smem + 8192 + d * 128;
      bf16x8 v0 = *(const bf16x8*)(vr + (((hi) ^ (d & 7)) * 16));
      bf16x8 v1 = *(const bf16x8*)(vr + (((4 + hi) ^ (d & 7)) * 16));
      oacc[f] = MFMA16(pa0, v0, oacc[f]);
      oacc[f] = MFMA16(pa1, v1, oacc[f]);
    }
  }

  // ---- epilogue: normalize and store f32 ----
  float inv = 1.f / l_run;   // softmax layout (q = rl)
  #pragma unroll
  for (int r = 0; r < 4; ++r) {
    float ir = __shfl(inv, (l & 48) | (hi * 4 + r));
    int row = b * TT + t0w + hi * 4 + r;
    #pragma unroll
    for (int f = 0; f < 4; ++f)
      out[(size_t)row * HS + f * 16 + rl] = oacc[f][r] * ir;
  }
}

extern "C" void kernel_launch(void* const* d_in, const int* in_sizes, int n_in,
                              void* d_out, int out_size, void* d_ws, size_t ws_size,
                              hipStream_t stream) {
  // setup_inputs dict order: x, w_key, w_query, w_value
  const float* x  = (const float*)d_in[0];
  const float* wk = (const float*)d_in[1];
  const float* wq = (const float*)d_in[2];
  const float* wv = (const float*)d_in[3];
  float* out = (float*)d_out;

  unsigned short* wp    = (unsigned short*)d_ws;        // 196608 el = 384 KB
  unsigned short* q_ws  = wp + 196608;                  // 2 MB
  unsigned short* k_ws  = q_ws + (size_t)NROW * HS;     // 2 MB
  unsigned short* vt_ws = k_ws + (size_t)NROW * HS;     // 2 MB
  unsigned short* xbuf  = vt_ws + (size_t)NROW * HS;    // 33.5 MB

  prep_kernel<<<2048, 256, 0, stream>>>(x, wq, wk, wv, xbuf, wp);
  proj_mfma_kernel<<<NROW / 64, 512, 0, stream>>>(xbuf, wp, q_ws, k_ws, vt_ws);
  attn_mfma_kernel<<<BB * (TT / 64), 256, 0, stream>>>(q_ws, k_ws, vt_ws, out);
}

// Round 13
// 41.762 us; speedup vs baseline: 1.2308x; 1.2308x over previous
//
#include <hip/hip_runtime.h>
#include <hip/hip_bf16.h>
#include <math.h>

#define BB 4
#define TT 4096
#define CC 1024
#define HS 64
#define WIN 512
#define NROW (BB*TT)

typedef float f32x4 __attribute__((ext_vector_type(4)));
typedef short bf16x8 __attribute__((ext_vector_type(8)));

#define MFMA16(a, b, c) __builtin_amdgcn_mfma_f32_16x16x32_bf16((a), (b), (c), 0, 0, 0)

#define GLOAD_LDS(gp, lp) __builtin_amdgcn_global_load_lds( \
    (const __attribute__((address_space(1))) void*)(gp), \
    (__attribute__((address_space(3))) void*)(lp), 16, 0, 0)

__device__ inline unsigned short f2b(float f) {
  union { __hip_bfloat16 h; unsigned short u; } v;
  v.h = __float2bfloat16(f);   // HW RNE convert
  return v.u;
}

// ---------------- pack W into MFMA B-fragment order (bf16) ----------------
__global__ __launch_bounds__(256) void pack_w_kernel(
    const float* __restrict__ wq, const float* __restrict__ wk,
    const float* __restrict__ wv, unsigned short* __restrict__ wp)
{
  int t = blockIdx.x * 256 + threadIdx.x;   // 49152 threads
  int kg = t / 48;
  int nq = t % 48;
  int n0 = nq * 4;
  int m  = n0 >> 6;
  int c  = n0 & 63;
  const float* w = (m == 0) ? wq : (m == 1) ? wk : wv;
  float4 v = *(const float4*)&w[(size_t)kg * HS + c];
  int kt = kg >> 5;
  int hi = (kg >> 3) & 3;
  int j  = kg & 7;
  float vals[4] = {v.x, v.y, v.z, v.w};
  #pragma unroll
  for (int i = 0; i < 4; ++i) {
    int n  = n0 + i;
    int nb = n >> 4;
    int rl = n & 15;
    int lane = hi * 16 + rl;
    wp[((size_t)(kt * 12 + nb) * 64 + lane) * 8 + j] = f2b(vals[i]);
  }
}

// ---------------- Projection via MFMA (R11 structure) ----------------
__global__ __launch_bounds__(512) void proj_mfma_kernel(
    const float* __restrict__ x, const unsigned short* __restrict__ wp,
    unsigned short* __restrict__ q_ws, unsigned short* __restrict__ k_ws,
    unsigned short* __restrict__ vt_ws)
{
  __shared__ unsigned char lds[131072];  // xb0 16K | xb1 16K | wb0 48K | wb1 48K
  unsigned char* const xb0 = lds;
  unsigned char* const xb1 = lds + 16384;
  unsigned char* const wb0 = lds + 32768;
  unsigned char* const wb1 = lds + 81920;

  const int tid = threadIdx.x;
  const int l   = tid & 63;
  const int wid = tid >> 6;
  const int cq  = wid & 3;
  const int rh  = wid >> 2;
  const int rl  = l & 15;
  const int hi  = l >> 4;
  const int r0  = blockIdx.x * 64;

  f32x4 acc[2][3];
  #pragma unroll
  for (int g = 0; g < 2; ++g)
    #pragma unroll
    for (int j = 0; j < 3; ++j) acc[g][j] = (f32x4){0.f, 0.f, 0.f, 0.f};

  f32x4 xr[2][2];

#define SXL(KS) { \
    _Pragma("unroll") \
    for (int it = 0; it < 2; ++it) { \
      int u = it * 512 + tid; \
      const float* gp = x + (size_t)(r0 + (u >> 4)) * CC + (KS) * 128 + (u & 15) * 8; \
      xr[it][0] = *(const f32x4*)gp; \
      xr[it][1] = *(const f32x4*)(gp + 4); \
    } }

#define XPACK(XB) { \
    _Pragma("unroll") \
    for (int it = 0; it < 2; ++it) { \
      int u = it * 512 + tid; \
      int row = u >> 4, seg = u & 15; \
      uint4 pk; \
      pk.x = (unsigned)f2b(xr[it][0][0]) | ((unsigned)f2b(xr[it][0][1]) << 16); \
      pk.y = (unsigned)f2b(xr[it][0][2]) | ((unsigned)f2b(xr[it][0][3]) << 16); \
      pk.z = (unsigned)f2b(xr[it][1][0]) | ((unsigned)f2b(xr[it][1][1]) << 16); \
      pk.w = (unsigned)f2b(xr[it][1][2]) | ((unsigned)f2b(xr[it][1][3]) << 16); \
      *(uint4*)((XB) + row * 256 + (((seg ^ (row & 7))) << 4)) = pk; \
    } }

#define SW(KS, WB) { \
    const unsigned short* wsrc = wp + (size_t)(KS) * 24576; \
    _Pragma("unroll") \
    for (int i = 0; i < 6; ++i) { \
      int s = i * 512 + tid; \
      GLOAD_LDS(wsrc + s * 8, (WB) + s * 16); \
    } }

#define COMP(XB, WB) { \
    _Pragma("unroll") \
    for (int kt = 0; kt < 4; ++kt) { \
      bf16x8 afr[2]; \
      _Pragma("unroll") \
      for (int g = 0; g < 2; ++g) { \
        int row = rh * 32 + g * 16 + rl; \
        int seg = kt * 4 + hi; \
        afr[g] = *(const bf16x8*)((XB) + row * 256 + ((seg ^ (row & 7)) << 4)); \
      } \
      _Pragma("unroll") \
      for (int j = 0; j < 3; ++j) { \
        bf16x8 wf = *(const bf16x8*)((WB) + ((kt * 12 + cq * 3 + j) * 64 + l) * 16); \
        acc[0][j] = MFMA16(afr[0], wf, acc[0][j]); \
        acc[1][j] = MFMA16(afr[1], wf, acc[1][j]); \
      } \
    } }

  SXL(0)
  SW(0, wb0)
  XPACK(xb0)
  __syncthreads();

  #pragma unroll
  for (int ks = 0; ks < 8; ++ks) {
    unsigned char* const xc = (ks & 1) ? xb1 : xb0;
    unsigned char* const wc = (ks & 1) ? wb1 : wb0;
    unsigned char* const xn = (ks & 1) ? xb0 : xb1;
    unsigned char* const wn = (ks & 1) ? wb0 : wb1;
    if (ks < 7) { SXL(ks + 1) SW(ks + 1, wn) }
    COMP(xc, wc)
    if (ks < 7) { XPACK(xn) }
    __syncthreads();
  }
#undef SXL
#undef XPACK
#undef SW
#undef COMP

  #pragma unroll
  for (int g = 0; g < 2; ++g) {
    int rb = r0 + rh * 32 + g * 16;
    #pragma unroll
    for (int j = 0; j < 3; ++j) {
      int nb = cq * 3 + j;
      if (nb < 8) {
        unsigned short* dst = (nb < 4) ? q_ws : k_ws;
        int c = (nb & 3) * 16 + rl;
        #pragma unroll
        for (int r = 0; r < 4; ++r) {
          int row = rb + hi * 4 + r;
          dst[(size_t)row * HS + c] = f2b(acc[g][j][r]);
        }
      } else {
        int ch   = rb >> 6;
        int key0 = (rb & 63) + hi * 4;
        int d = (nb - 8) * 16 + rl;
        unsigned u0 = (unsigned)f2b(acc[g][j][0]) | ((unsigned)f2b(acc[g][j][1]) << 16);
        unsigned u1 = (unsigned)f2b(acc[g][j][2]) | ((unsigned)f2b(acc[g][j][3]) << 16);
        uint2 uu; uu.x = u0; uu.y = u1;
        *(uint2*)(vt_ws + (size_t)ch * 4096 + d * 64 + key0) = uu;
      }
    }
  }
}

// ---------------- Split-KV sliding-window flash attention via MFMA --------
// grid 512 blocks: blockIdx = (b*64+qt)*2 + split. Each block processes half
// the KV-chunk range of its 64-q tile (2 blocks/CU, halved serial chain),
// writing unnormalized partial O and per-q (m,l) to workspace.
__global__ __launch_bounds__(256) void attn_mfma_kernel(
    const unsigned short* __restrict__ q_ws, const unsigned short* __restrict__ k_ws,
    const unsigned short* __restrict__ vt_ws,
    float* __restrict__ op_ws, float* __restrict__ ml_ws)
{
  __shared__ uint4 smem4[1600];                 // 25600 B
  unsigned char* smem = (unsigned char*)smem4;  // K:[0,8K) Vt:[8K,16K) P:16K+

  const int tid = threadIdx.x;
  const int l   = tid & 63;
  const int wid = tid >> 6;
  const int rl  = l & 15;
  const int hi  = l >> 4;
  const int split = blockIdx.x & 1;
  const int bq  = blockIdx.x >> 1;
  const int b   = bq >> 6;
  const int qt  = bq & 63;
  const int t0  = qt * 64;
  const int t0w = t0 + wid * 16;

  // Q B-fragments: lane = q row t0w+rl, d = hi*8+j (+32)
  const unsigned short* qrow = q_ws + (size_t)(b * TT + t0w + rl) * HS;
  bf16x8 qb0 = *(const bf16x8*)(qrow + hi * 8);
  bf16x8 qb1 = *(const bf16x8*)(qrow + 32 + hi * 8);

  f32x4 oacc[4];
  #pragma unroll
  for (int i = 0; i < 4; ++i) oacc[i] = (f32x4){0.f, 0.f, 0.f, 0.f};
  float m_run = -INFINITY, l_run = 0.f;

  int s_lo = t0 - WIN; if (s_lo < 0) s_lo = 0;
  const int nch = (t0 + 64 - s_lo) >> 6;     // 1..10 chunks
  const int h   = nch >> 1;
  const int c_lo = split ? (s_lo + h * 64) : s_lo;
  const int c_hi = split ? (t0 + 64) : (s_lo + h * 64);

  unsigned char* pbase = smem + 16384 + wid * 2304 + rl * 144;

  for (int sc = c_lo; sc < c_hi; sc += 64) {
    __syncthreads();
    // ---- stage K and Vt chunk (64x64 bf16 each), XOR-swizzled rows ----
    {
      const unsigned short* kg = k_ws + (size_t)(b * TT + sc) * HS;
      const unsigned short* vg = vt_ws + (size_t)((b * TT + sc) >> 6) * 4096;
      #pragma unroll
      for (int i = 0; i < 2; ++i) {
        int idx = tid + i * 256;
        int row = idx >> 3;
        int c16 = idx & 7;
        uint4 kv = *(const uint4*)(kg + row * 64 + c16 * 8);
        uint4 vv = *(const uint4*)(vg + row * 64 + c16 * 8);
        *(uint4*)(smem + row * 128 + ((c16 ^ (row & 7)) * 16)) = kv;
        *(uint4*)(smem + 8192 + row * 128 + ((c16 ^ (row & 7)) * 16)) = vv;
      }
    }
    __syncthreads();

    // ---- S^T = K @ Q^T ----
    f32x4 sacc[4];
    #pragma unroll
    for (int i = 0; i < 4; ++i) sacc[i] = (f32x4){0.f, 0.f, 0.f, 0.f};
    #pragma unroll
    for (int kb = 0; kb < 4; ++kb) {
      int row = kb * 16 + rl;
      unsigned char* kr = smem + row * 128;
      bf16x8 k0 = *(const bf16x8*)(kr + (((hi) ^ (row & 7)) * 16));
      bf16x8 k1 = *(const bf16x8*)(kr + (((4 + hi) ^ (row & 7)) * 16));
      sacc[kb] = MFMA16(k0, qb0, sacc[kb]);
      sacc[kb] = MFMA16(k1, qb1, sacc[kb]);
    }

    // ---- mask + scale + online softmax (lane owns one q = t0w+rl) ----
    const int tg = t0w + rl;
    float p[16];
    float tm = -INFINITY;
    bool full = (sc + 63 <= t0w) && (sc >= t0w - 496);
    #pragma unroll
    for (int kb = 0; kb < 4; ++kb)
      #pragma unroll
      for (int r = 0; r < 4; ++r) {
        float v = sacc[kb][r] * 0.125f;
        if (!full) {
          int key = sc + kb * 16 + hi * 4 + r;
          int diff = tg - key;
          v = (diff >= 0 && diff < WIN) ? v : -INFINITY;
        }
        p[kb * 4 + r] = v;
        tm = fmaxf(tm, v);
      }
    tm = fmaxf(tm, __shfl_xor(tm, 16));
    tm = fmaxf(tm, __shfl_xor(tm, 32));
    float m_new = fmaxf(m_run, tm);
    float fac  = (m_new == -INFINITY) ? 1.f : __expf(m_run - m_new);
    float msub = (m_new == -INFINITY) ? 0.f : m_new;
    float lsum = 0.f;
    #pragma unroll
    for (int i = 0; i < 16; ++i) { p[i] = __expf(p[i] - msub); lsum += p[i]; }
    lsum += __shfl_xor(lsum, 16);
    lsum += __shfl_xor(lsum, 32);
    l_run = l_run * fac + lsum;
    m_run = m_new;

    // ---- P -> wave-private LDS ----
    #pragma unroll
    for (int kb = 0; kb < 4; ++kb) {
      unsigned u0 = (unsigned)f2b(p[kb * 4 + 0]) | ((unsigned)f2b(p[kb * 4 + 1]) << 16);
      unsigned u1 = (unsigned)f2b(p[kb * 4 + 2]) | ((unsigned)f2b(p[kb * 4 + 3]) << 16);
      uint2 uu; uu.x = u0; uu.y = u1;
      *(uint2*)(pbase + kb * 32 + hi * 8) = uu;
    }

    // ---- rescale O (redistribute to PV C-layout q = hi*4+r) ----
    #pragma unroll
    for (int r = 0; r < 4; ++r) {
      float fr = __shfl(fac, (l & 48) | (hi * 4 + r));
      oacc[0][r] *= fr; oacc[1][r] *= fr; oacc[2][r] *= fr; oacc[3][r] *= fr;
    }

    // ---- PV ----
    bf16x8 pa0 = *(const bf16x8*)(pbase + hi * 16);
    bf16x8 pa1 = *(const bf16x8*)(pbase + 64 + hi * 16);
    #pragma unroll
    for (int f = 0; f < 4; ++f) {
      int d = f * 16 + rl;
      unsigned char* vr = smem + 8192 + d * 128;
      bf16x8 v0 = *(const bf16x8*)(vr + (((hi) ^ (d & 7)) * 16));
      bf16x8 v1 = *(const bf16x8*)(vr + (((4 + hi) ^ (d & 7)) * 16));
      oacc[f] = MFMA16(pa0, v0, oacc[f]);
      oacc[f] = MFMA16(pa1, v1, oacc[f]);
    }
  }

  // ---- epilogue: store UNNORMALIZED partial O + (m,l) ----
  #pragma unroll
  for (int r = 0; r < 4; ++r) {
    size_t gq = (size_t)(b * TT + t0w + hi * 4 + r);
    #pragma unroll
    for (int f = 0; f < 4; ++f)
      op_ws[(gq * 2 + split) * HS + f * 16 + rl] = oacc[f][r];
  }
  if (hi == 0) {
    size_t gq = (size_t)(b * TT + t0w + rl);
    ml_ws[gq * 4 + split * 2 + 0] = m_run;
    ml_ws[gq * 4 + split * 2 + 1] = l_run;
  }
}

// ---------------- split-KV combine: out = softmax-merge of 2 partials ------
__global__ __launch_bounds__(256) void reduce_kernel(
    const float* __restrict__ op_ws, const float* __restrict__ ml_ws,
    float* __restrict__ out)
{
  int gid = blockIdx.x * 256 + threadIdx.x;   // 262144
  int r  = gid >> 4;
  int c4 = (gid & 15) * 4;
  float4 mlv = *(const float4*)&ml_ws[(size_t)r * 4];  // m0,l0,m1,l1
  float M  = fmaxf(mlv.x, mlv.z);
  float a0 = __expf(mlv.x - M);   // m0=-inf -> 0
  float a1 = __expf(mlv.z - M);
  float inv = 1.f / (a0 * mlv.y + a1 * mlv.w);
  f32x4 o0 = *(const f32x4*)&op_ws[((size_t)r * 2 + 0) * HS + c4];
  f32x4 o1 = *(const f32x4*)&op_ws[((size_t)r * 2 + 1) * HS + c4];
  f32x4 o;
  #pragma unroll
  for (int i = 0; i < 4; ++i) o[i] = (o0[i] * a0 + o1[i] * a1) * inv;
  *(f32x4*)&out[(size_t)r * HS + c4] = o;
}

extern "C" void kernel_launch(void* const* d_in, const int* in_sizes, int n_in,
                              void* d_out, int out_size, void* d_ws, size_t ws_size,
                              hipStream_t stream) {
  // setup_inputs dict order: x, w_key, w_query, w_value
  const float* x  = (const float*)d_in[0];
  const float* wk = (const float*)d_in[1];
  const float* wq = (const float*)d_in[2];
  const float* wv = (const float*)d_in[3];
  float* out = (float*)d_out;

  unsigned short* wp    = (unsigned short*)d_ws;        // 384 KB
  unsigned short* q_ws  = wp + 196608;                  // 2 MB
  unsigned short* k_ws  = q_ws + (size_t)NROW * HS;     // 2 MB
  unsigned short* vt_ws = k_ws + (size_t)NROW * HS;     // 2 MB
  float* op_ws = (float*)(vt_ws + (size_t)NROW * HS);   // 8.4 MB
  float* ml_ws = op_ws + (size_t)NROW * 2 * HS;         // 256 KB

  pack_w_kernel<<<192, 256, 0, stream>>>(wq, wk, wv, wp);
  proj_mfma_kernel<<<NROW / 64, 512, 0, stream>>>(x, wp, q_ws, k_ws, vt_ws);
  attn_mfma_kernel<<<BB * (TT / 64) * 2, 256, 0, stream>>>(q_ws, k_ws, vt_ws, op_ws, ml_ws);
  reduce_kernel<<<NROW * HS / 4 / 256, 256, 0, stream>>>(op_ws, ml_ws, out);
}